// Round 2
// baseline (397.417 us; speedup 1.0000x reference)
//
#include <hip/hip_runtime.h>

typedef unsigned short u16;
typedef unsigned int u32;
typedef __bf16 bf16x8 __attribute__((ext_vector_type(8)));
typedef float f32x4 __attribute__((ext_vector_type(4)));

// Problem constants: B=2, S=2048, D=2048, H=16, HD=128, F=3*H*HD=6144, M=B*S=4096

__device__ __forceinline__ u16 f2bf(float x) {
  __bf16 h = (__bf16)x;
  return __builtin_bit_cast(u16, h);
}

// async global->LDS, 16B per lane. LDS dest must be wave-uniform; HW scatters lane i to base+16*i.
__device__ __forceinline__ void async_copy16(void* lds, const void* g) {
  __builtin_amdgcn_global_load_lds((const __attribute__((address_space(1))) void*)g,
                                   (__attribute__((address_space(3))) void*)lds, 16, 0, 0);
}

// ---------------- fused cast fp32 -> bf16 for all three tensors ----------------
__global__ __launch_bounds__(256) void cast_all(const float* __restrict__ hidden,
                                                const float* __restrict__ wqkv,
                                                const float* __restrict__ wo,
                                                u16* __restrict__ xb,
                                                u16* __restrict__ wqb,
                                                u16* __restrict__ wob) {
  int i = blockIdx.x * 256 + threadIdx.x;  // 6291456 vec4 total
  const float* s;
  u16* d;
  int off;
  if (i < 2097152) { s = hidden; d = xb; off = i; }
  else if (i < 2097152 + 3145728) { s = wqkv; d = wqb; off = i - 2097152; }
  else { s = wo; d = wob; off = i - (2097152 + 3145728); }
  float4 v = ((const float4*)s)[off];
  ushort4 o;
  o.x = f2bf(v.x); o.y = f2bf(v.y); o.z = f2bf(v.z); o.w = f2bf(v.w);
  ((ushort4*)d)[off] = o;
}

// ---------------- QKV projection GEMM (256x256x64, 8-wave, 8-phase) + fused RoPE ------
// C[m,f] = sum_d X[m,d]*W[f,d]. M=4096, N=6144, K=2048. 8-phase counted-vmcnt schedule,
// m201-faithful ledger (3 half-tiles in flight, vmcnt(6), youngest waited load is 3
// phases old). Iteration t reads buf0=tile 2t (phi1-4) and buf1=tile 2t+1 (phi5-8).
// Stage slots: phi1: buf1.B0(k=2t+1) | phi2: buf0.A0(2t+2) | phi3: buf0.B1 |
// phi4: buf0.A1 +VMW6 | phi5: buf0.B0 | phi6: buf1.A0(2t+3) | phi7: buf1.B1 |
// phi8: buf1.A1 +VMW6. Drain@phi4 completes {prev6,7,8,phi1} = buf1's 4 pieces;
// drain@phi8 completes {phi2,3,4,5} = buf0-next. Overwrite slots all >= 1 barrier
// after the piece's last read (B0 read phi1&4 -> staged phi5; buf1.B0 read phi5&8 ->
// staged next phi1). Per-row chunk-XOR swizzle keeps ds_read_b128 conflict-free.
// Wave->column remap keeps RoPE pairs (hd,hd+64) in-lane and head/which wave-uniform.

__device__ __forceinline__ void lda4(bf16x8 (&af)[4][2], const u16* base, int row, int c0, int c1) {
#pragma unroll
  for (int mf = 0; mf < 4; mf++) {
    const u16* p = base + (row + mf * 16) * 64;
    af[mf][0] = *(const bf16x8*)(p + c0);
    af[mf][1] = *(const bf16x8*)(p + c1);
  }
}

__device__ __forceinline__ void ldb2(bf16x8 (&bfr)[2][2], const u16* base, int row, int c0, int c1) {
#pragma unroll
  for (int nf = 0; nf < 2; nf++) {
    const u16* p = base + (row + nf * 16) * 64;
    bfr[nf][0] = *(const bf16x8*)(p + c0);
    bfr[nf][1] = *(const bf16x8*)(p + c1);
  }
}

#define FENCE() asm volatile("" ::: "memory")
#define LGKM0() asm volatile("s_waitcnt lgkmcnt(0)" ::: "memory")
#define VMW6() asm volatile("s_waitcnt vmcnt(6)" ::: "memory")
#define VMW0() asm volatile("s_waitcnt vmcnt(0)" ::: "memory")
#define BAR() __builtin_amdgcn_s_barrier()
#define PH_TOP() \
  FENCE(); BAR(); LGKM0(); __builtin_amdgcn_sched_barrier(0); __builtin_amdgcn_s_setprio(1)
#define PH_BOT() __builtin_amdgcn_s_setprio(0); FENCE(); BAR()

#define MFMA_Q(MH, NH)                                                                   \
  _Pragma("unroll") for (int ks = 0; ks < 2; ks++)                                       \
  _Pragma("unroll") for (int mf = 0; mf < 4; mf++)                                       \
  _Pragma("unroll") for (int nf = 0; nf < 2; nf++)                                       \
      acc[(MH)*4 + mf][(NH)*2 + nf] = __builtin_amdgcn_mfma_f32_16x16x32_bf16(           \
          af[mf][ks], bfr[nf][ks], acc[(MH)*4 + mf][(NH)*2 + nf], 0, 0, 0);

// stage one half-tile (128 rows x 64 cols): 2 global_load_lds per thread
#define STG_A(DB, H, KT)                                                                   \
  {                                                                                        \
    async_copy16(ldsA + (DB)*32768 + ((H)*64 + w8) * 128, Ag + aoff[H][0] + (KT)*128);     \
    async_copy16(ldsA + (DB)*32768 + (128 + (H)*64 + w8) * 128, Ag + aoff[H][1] + (KT)*128); \
  }
#define STG_B(DB, H, KT)                                                                   \
  {                                                                                        \
    async_copy16(ldsB + (DB)*32768 + ((H)*64 + w8) * 128, Bg + boff[H][0] + (KT)*128);     \
    async_copy16(ldsB + (DB)*32768 + (128 + (H)*64 + w8) * 128, Bg + boff[H][1] + (KT)*128); \
  }

template <bool MORE>
__device__ __forceinline__ void qkv_iter(const u16* As, const u16* Bs, char* ldsA, char* ldsB,
                                         const char* Ag, const char* Bg,
                                         const u32 (&aoff)[2][2], const u32 (&boff)[2][2],
                                         int w8, int arow0, int brow0, int c0, int c1,
                                         int k1, int k2, int k3,
                                         bf16x8 (&af)[4][2], bf16x8 (&bfr)[2][2],
                                         f32x4 (&acc)[8][4]) {
  const int arow1 = arow0 + 256;
  const int brow1 = brow0 + 256;
  // phi1: buf0 quad(0,0) | stage buf1.B0 (k1 = 2t+1)
  lda4(af, As, arow0, c0, c1);
  ldb2(bfr, Bs, brow0, c0, c1);
  STG_B(1, 0, k1);
  PH_TOP(); MFMA_Q(0, 0); PH_BOT();
  // phi2: buf0 quad(0,1) | stage buf0.A0 (k2 = 2t+2)
  ldb2(bfr, Bs, brow0 + 64, c0, c1);
  if (MORE) { STG_A(0, 0, k2); }
  PH_TOP(); MFMA_Q(0, 1); PH_BOT();
  // phi3: buf0 quad(1,1) | stage buf0.B1 (k2)
  lda4(af, As, arow0 + 64, c0, c1);
  if (MORE) { STG_B(0, 1, k2); }
  PH_TOP(); MFMA_Q(1, 1); PH_BOT();
  // phi4: buf0 quad(1,0) | stage buf0.A1 (k2) | drain buf1's 4 pieces
  ldb2(bfr, Bs, brow0, c0, c1);
  if (MORE) { STG_A(0, 1, k2); }
  PH_TOP(); MFMA_Q(1, 0);
  __builtin_amdgcn_s_setprio(0);
  if (MORE) { VMW6(); } else { VMW0(); }
  FENCE(); BAR();
  // phi5: buf1 quad(0,0) | stage buf0.B0 (k2)
  lda4(af, As, arow1, c0, c1);
  ldb2(bfr, Bs, brow1, c0, c1);
  if (MORE) { STG_B(0, 0, k2); }
  PH_TOP(); MFMA_Q(0, 0); PH_BOT();
  // phi6: buf1 quad(0,1) | stage buf1.A0 (k3 = 2t+3)
  ldb2(bfr, Bs, brow1 + 64, c0, c1);
  if (MORE) { STG_A(1, 0, k3); }
  PH_TOP(); MFMA_Q(0, 1); PH_BOT();
  // phi7: buf1 quad(1,1) | stage buf1.B1 (k3)
  lda4(af, As, arow1 + 64, c0, c1);
  if (MORE) { STG_B(1, 1, k3); }
  PH_TOP(); MFMA_Q(1, 1); PH_BOT();
  // phi8: buf1 quad(1,0) | stage buf1.A1 (k3) | drain buf0-next
  ldb2(bfr, Bs, brow1, c0, c1);
  if (MORE) { STG_A(1, 1, k3); }
  PH_TOP(); MFMA_Q(1, 0);
  __builtin_amdgcn_s_setprio(0);
  if (MORE) { VMW6(); }
  FENCE(); BAR();
}

__global__ __launch_bounds__(512, 2) void gemm_qkv(const u16* __restrict__ A,
                                                   const u16* __restrict__ W,
                                                   const float* __restrict__ cosb,
                                                   const float* __restrict__ sinb,
                                                   u16* __restrict__ Qb,
                                                   u16* __restrict__ Kb,
                                                   u16* __restrict__ Vt) {
  extern __shared__ u16 smem[];  // 131072 B dynamic
  u16* As = smem;                // [2 buf][256 rows][64], row-chunk-XOR swizzled
  u16* Bs = smem + 32768;
  char* ldsA = (char*)As;
  char* ldsB = (char*)Bs;
  const char* Ag = (const char*)A;
  const char* Bg = (const char*)W;

  const int tid = threadIdx.x;
  const int lane = tid & 63;
  const int w = tid >> 6;   // 0..7
  const int wm = w >> 2;    // 0..1
  const int wn = w & 3;     // 0..3
  const int r16 = lane & 15;
  const int g4 = lane >> 4;
  const int rsw = r16 & 7;
  const int w8 = w * 8;
  const int l8 = lane >> 3;
  const int gch = (lane & 7) ^ l8;  // global chunk feeding this lane's LDS slot

  // XCD-aware bijective swizzle (384 = 8*48)
  const int nblk = blockIdx.x;
  const int swz = (nblk & 7) * 48 + (nblk >> 3);
  const int bm = (swz & 15) * 256;
  const int by = swz >> 4;  // 0..23
  const int bn = by * 256;

  u32 aoff[2][2], boff[2][2];
#pragma unroll
  for (int h = 0; h < 2; h++) {
#pragma unroll
    for (int j = 0; j < 2; j++) {
      int row = j * 128 + h * 64 + w8 + l8;
      aoff[h][j] = (u32)(bm + row) * 4096u + (u32)gch * 16u;
      boff[h][j] = (u32)(bn + row) * 4096u + (u32)gch * 16u;
    }
  }

  const int c0 = (g4 ^ rsw) * 8;
  const int c1 = ((4 + g4) ^ rsw) * 8;
  const int arow0 = wm * 128 + r16;
  const int brow0 = (wn >> 1) * 128 + (wn & 1) * 32 + r16;

  bf16x8 af[4][2], bfr[2][2];
  f32x4 acc[8][4];
  const f32x4 fzero = {0.0f, 0.0f, 0.0f, 0.0f};
#pragma unroll
  for (int i = 0; i < 8; i++)
#pragma unroll
    for (int j = 0; j < 4; j++) acc[i][j] = fzero;

  // prologue: buf0 (tile 0, all 4 pieces) then buf1 (tile 1: A0, B1, A1).
  // VMW6 drains the 4 oldest = buf0; residue {buf1.A0,B1,A1} matches steady state.
  STG_A(0, 0, 0); STG_B(0, 0, 0); STG_B(0, 1, 0); STG_A(0, 1, 0);
  STG_A(1, 0, 1); STG_B(1, 1, 1); STG_A(1, 1, 1);
  VMW6();
  FENCE(); BAR();

#pragma unroll 1
  for (int t = 0; t < 15; t++) {
    qkv_iter<true>(As, Bs, ldsA, ldsB, Ag, Bg, aoff, boff, w8, arow0, brow0, c0, c1,
                   2 * t + 1, 2 * t + 2, 2 * t + 3, af, bfr, acc);
  }
  qkv_iter<false>(As, Bs, ldsA, ldsB, Ag, Bg, aoff, boff, w8, arow0, brow0, c0, c1,
                  31, 31, 31, af, bfr, acc);

  // ---- epilogue: RoPE (Q,K) / transpose-scatter (V). head/which wave-uniform.
  const int blk128 = by * 2 + (wn >> 1);
  const int which = blk128 % 3;
  const int head = blk128 / 3;
  const float qs = (which == 0) ? 0.08838834764831845f * 1.4426950408889634f : 1.0f;
  const int hb = (wn & 1) * 32;

#pragma unroll
  for (int mi = 0; mi < 8; mi++) {
#pragma unroll
    for (int r = 0; r < 4; r++) {
      int row = bm + wm * 128 + mi * 16 + g4 * 4 + r;  // global m = b*S+s
      int bb = row >> 11;
      int s = row & 2047;
      size_t bhIdx = (size_t)(bb * 16 + head);
      if (which == 2) {
#pragma unroll
        for (int ni = 0; ni < 4; ni++) {
          int hd = hb + (ni & 1) * 16 + (ni >> 1) * 64 + r16;
          Vt[(bhIdx * 128 + hd) * 2048 + s] = f2bf(acc[mi][ni][r]);  // V^T: [bh][hd][s]
        }
      } else {
        u16* dst = (which ? Kb : Qb) + (bhIdx * 2048 + (size_t)s) * 128;
#pragma unroll
        for (int ni = 0; ni < 2; ni++) {
          int hd = hb + ni * 16 + r16;  // <64; pair is hd+64 in acc[mi][ni+2]
          float c = cosb[s * 128 + hd] * qs;
          float sn = sinb[s * 128 + hd] * qs;
          float x1 = acc[mi][ni][r], x2 = acc[mi][ni + 2][r];
          dst[hd] = f2bf(x1 * c - x2 * sn);
          dst[hd + 64] = f2bf(x2 * c + x1 * sn);
        }
      }
    }
  }
}

#undef STG_A
#undef STG_B
#undef MFMA_Q
#undef PH_TOP
#undef PH_BOT

// ---------------- Flash attention: 128-query x 128-key tiles, 512 threads --------------
// (unchanged)
__global__ __launch_bounds__(512) void flash_attn(const u16* __restrict__ Q,
                                                  const u16* __restrict__ K,
                                                  const u16* __restrict__ Vt,
                                                  u16* __restrict__ O) {
  __shared__ __align__(16) u16 Ks[2][128 * 128];
  __shared__ __align__(16) u16 Vs[2][128 * 128];
  __shared__ __align__(16) u16 Ps[8 * 16 * 64];  // per-wave [q][64 keys], XOR-swizzled
  const int tid = threadIdx.x;
  const int lane = tid & 63;
  const int wave = tid >> 6;  // 0..7
  const int bh = blockIdx.y;
  const int r16 = lane & 15;
  const int g4 = lane >> 4;
  const int rsw = r16 & 7;
  const u16* Qh = Q + (size_t)bh * 2048 * 128;
  const u16* Kh = K + (size_t)bh * 2048 * 128;
  const u16* Vh = Vt + (size_t)bh * 128 * 2048;
  const int b = bh >> 4;
  const int h = bh & 15;

  int koff[4], voff[4], ldsOff[4];
#pragma unroll
  for (int i = 0; i < 4; i++) {
    int r = (wave * 4 + i) * 4 + (lane >> 4);  // 0..127
    int c = (lane & 15) ^ (r & 7);
    koff[i] = r * 128 + c * 8;
    voff[i] = r * 2048 + c * 8;
    ldsOff[i] = (wave * 4 + i) * 512;
  }

#pragma unroll 1
  for (int pass = 0; pass < 2; pass++) {
    const int T = pass == 0 ? (int)blockIdx.x : 15 - (int)blockIdx.x;
    const int qg = T * 128 + wave * 16 + r16;
    const int nk = T + 1;

    bf16x8 qf[4];
#pragma unroll
    for (int ks = 0; ks < 4; ks++)
      qf[ks] = *(const bf16x8*)(Qh + (size_t)qg * 128 + ks * 32 + g4 * 8);

    f32x4 o[8];
    f32x4 zero = {0.0f, 0.0f, 0.0f, 0.0f};
#pragma unroll
    for (int c = 0; c < 8; c++) o[c] = zero;
    float m_i = -__builtin_inff();
    float l_i = 0.0f;

    __syncthreads();
#pragma unroll
    for (int i = 0; i < 4; i++) {
      async_copy16(&Ks[0][ldsOff[i]], Kh + koff[i]);
      async_copy16(&Vs[0][ldsOff[i]], Vh + voff[i]);
    }

    int cur = 0;
    for (int u = 0; u < nk; u++) {
      __syncthreads();
      if (u + 1 < nk) {
#pragma unroll
        for (int i = 0; i < 4; i++) {
          async_copy16(&Ks[cur ^ 1][ldsOff[i]], Kh + (size_t)(u + 1) * 16384 + koff[i]);
          async_copy16(&Vs[cur ^ 1][ldsOff[i]], Vh + (size_t)(u + 1) * 128 + voff[i]);
        }
      }

      f32x4 sacc[8];
#pragma unroll
      for (int n = 0; n < 8; n++) sacc[n] = zero;
#pragma unroll
      for (int n = 0; n < 8; n++) {
#pragma unroll
        for (int ks = 0; ks < 4; ks++) {
          bf16x8 kf = *(const bf16x8*)(&Ks[cur][(n * 16 + r16) * 128 + ((ks * 4 + g4) ^ rsw) * 8]);
          sacc[n] = __builtin_amdgcn_mfma_f32_16x16x32_bf16(kf, qf[ks], sacc[n], 0, 0, 0);
        }
      }

      if (u == nk - 1) {
#pragma unroll
        for (int n = 0; n < 8; n++)
#pragma unroll
          for (int r = 0; r < 4; r++) {
            int key = u * 128 + 16 * n + g4 * 4 + r;
            if (key > qg) sacc[n][r] = -__builtin_inff();
          }
      }
      float vmax = -__builtin_inff();
#pragma unroll
      for (int n = 0; n < 8; n++)
#pragma unroll
        for (int r = 0; r < 4; r++) vmax = fmaxf(vmax, sacc[n][r]);
      vmax = fmaxf(vmax, __shfl_xor(vmax, 16));
      vmax = fmaxf(vmax, __shfl_xor(vmax, 32));
      float mn = fmaxf(m_i, vmax);
      float alpha = exp2f(m_i - mn);
      m_i = mn;

#pragma unroll
      for (int c = 0; c < 8; c++)
#pragma unroll
        for (int r = 0; r < 4; r++) o[c][r] *= alpha;

      float ssum = 0.0f;
      u16* Pw = &Ps[wave * 1024];
#pragma unroll
      for (int half = 0; half < 2; half++) {
#pragma unroll
        for (int nl = 0; nl < 4; nl++) {
          int n = half * 4 + nl;
          float p0 = exp2f(sacc[n][0] - mn);
          float p1 = exp2f(sacc[n][1] - mn);
          float p2 = exp2f(sacc[n][2] - mn);
          float p3 = exp2f(sacc[n][3] - mn);
          ssum += (p0 + p1) + (p2 + p3);
          ushort4 pk;
          pk.x = f2bf(p0); pk.y = f2bf(p1); pk.z = f2bf(p2); pk.w = f2bf(p3);
          *(ushort4*)(&Pw[r16 * 64 + ((2 * nl + (g4 >> 1)) ^ rsw) * 8 + (g4 & 1) * 4]) = pk;
        }
#pragma unroll
        for (int ks2 = 0; ks2 < 2; ks2++) {
          bf16x8 pf = *(const bf16x8*)(&Pw[r16 * 64 + ((ks2 * 4 + g4) ^ rsw) * 8]);
          int kv = half * 2 + ks2;
#pragma unroll
          for (int c = 0; c < 8; c++) {
            bf16x8 vf = *(const bf16x8*)(&Vs[cur][(c * 16 + r16) * 128 + ((kv * 4 + g4) ^ rsw) * 8]);
            o[c] = __builtin_amdgcn_mfma_f32_16x16x32_bf16(vf, pf, o[c], 0, 0, 0);
          }
        }
      }
      ssum += __shfl_xor(ssum, 16);
      ssum += __shfl_xor(ssum, 32);
      l_i = l_i * alpha + ssum;
      cur ^= 1;
    }

    float rl = 1.0f / l_i;
    u16* dst = O + ((size_t)(b * 2048 + qg)) * 2048 + h * 128;
#pragma unroll
    for (int c = 0; c < 8; c++) {
      ushort4 pk;
      pk.x = f2bf(o[c][0] * rl);
      pk.y = f2bf(o[c][1] * rl);
      pk.z = f2bf(o[c][2] * rl);
      pk.w = f2bf(o[c][3] * rl);
      *(ushort4*)(dst + c * 16 + g4 * 4) = pk;
    }
  }
}

// ---------------- Output projection GEMM (unchanged) ----------------
__global__ __launch_bounds__(256) void gemm_out(const u16* __restrict__ A,
                                                const u16* __restrict__ W,
                                                float* __restrict__ out) {
  __shared__ __align__(16) u16 As[128 * 64];
  __shared__ __align__(16) u16 Bs[128 * 64];
  const int tid = threadIdx.x;
  const int lane = tid & 63;
  const int wave = tid >> 6;
  const int wm = (wave >> 1) * 64;
  const int wn = (wave & 1) * 64;
  const int r16 = lane & 15;
  const int g4 = lane >> 4;
  const int rsw = r16 & 7;
  const int bm = blockIdx.x * 128;
  const int bn = blockIdx.y * 128;

  size_t aoff[4], boff[4];
  u16* ldsA[4];
  u16* ldsB[4];
#pragma unroll
  for (int i = 0; i < 4; i++) {
    int row = wave * 32 + i * 8 + (lane >> 3);
    int c = (lane & 7) ^ (row & 7);
    aoff[i] = (size_t)(bm + row) * 2048 + c * 8;
    boff[i] = (size_t)(bn + row) * 2048 + c * 8;
    ldsA[i] = &As[(wave * 4 + i) * 512];
    ldsB[i] = &Bs[(wave * 4 + i) * 512];
  }

  f32x4 acc[4][4];
  f32x4 zero = {0.0f, 0.0f, 0.0f, 0.0f};
#pragma unroll
  for (int m = 0; m < 4; m++)
#pragma unroll
    for (int n = 0; n < 4; n++) acc[m][n] = zero;

  for (int kt = 0; kt < 2048; kt += 64) {
    __syncthreads();
#pragma unroll
    for (int i = 0; i < 4; i++) {
      async_copy16(ldsA[i], A + aoff[i] + kt);
      async_copy16(ldsB[i], W + boff[i] + kt);
    }
    __syncthreads();
#pragma unroll
    for (int ks = 0; ks < 2; ks++) {
      bf16x8 af[4], bfr[4];
#pragma unroll
      for (int m = 0; m < 4; m++)
        af[m] = *(const bf16x8*)(&As[(wm + m * 16 + r16) * 64 + ((ks * 4 + g4) ^ rsw) * 8]);
#pragma unroll
      for (int n = 0; n < 4; n++)
        bfr[n] = *(const bf16x8*)(&Bs[(wn + n * 16 + r16) * 64 + ((ks * 4 + g4) ^ rsw) * 8]);
#pragma unroll
      for (int m = 0; m < 4; m++)
#pragma unroll
        for (int n = 0; n < 4; n++)
          acc[m][n] = __builtin_amdgcn_mfma_f32_16x16x32_bf16(af[m], bfr[n], acc[m][n], 0, 0, 0);
    }
  }

#pragma unroll
  for (int m = 0; m < 4; m++) {
#pragma unroll
    for (int n = 0; n < 4; n++) {
#pragma unroll
      for (int r = 0; r < 4; r++) {
        int row = bm + wm + m * 16 + g4 * 4 + r;
        int col = bn + wn + n * 16 + r16;
        out[(size_t)row * 2048 + col] = acc[m][n][r];
      }
    }
  }
}

extern "C" void kernel_launch(void* const* d_in, const int* in_sizes, int n_in,
                              void* d_out, int out_size, void* d_ws, size_t ws_size,
                              hipStream_t stream) {
  const float* hidden = (const float*)d_in[0];  // [2,2048,2048]
  const float* cosb   = (const float*)d_in[1];  // [2048,128]
  const float* sinb   = (const float*)d_in[2];  // [2048,128]
  const float* w_qkv  = (const float*)d_in[3];  // [3,2048,2048] -> flat [6144,2048]
  const float* w_o    = (const float*)d_in[4];  // [2048,2048]
  float* out = (float*)d_out;                   // [2,2048,2048] fp32

  char* ws = (char*)d_ws;
  u16* Xbf    = (u16*)(ws);                 // 16 MiB
  u16* Wqkvbf = (u16*)(ws + 16777216);      // 24 MiB
  u16* Wobf   = (u16*)(ws + 41943040);      // 8 MiB
  u16* Qb     = (u16*)(ws + 50331648);      // [B,H,S,HD] 16 MiB
  u16* Kb     = (u16*)(ws + 67108864);      // [B,H,S,HD] 16 MiB
  u16* Vt     = (u16*)(ws + 83886080);      // [B,H,HD,S] 16 MiB
  u16* Ob     = (u16*)(ws + 100663296);     // [B,S,H,HD] 16 MiB (end 112 MiB)

  static int attr_done = 0;
  if (!attr_done) {
    (void)hipFuncSetAttribute((const void*)gemm_qkv,
                              hipFuncAttributeMaxDynamicSharedMemorySize, 131072);
    attr_done = 1;
  }

  cast_all<<<24576, 256, 0, stream>>>(hidden, w_qkv, w_o, Xbf, Wqkvbf, Wobf);
  gemm_qkv<<<384, 512, 131072, stream>>>(Xbf, Wqkvbf, cosb, sinb, Qb, Kb, Vt);
  flash_attn<<<dim3(8, 32), 512, 0, stream>>>(Qb, Kb, Vt, Ob);
  gemm_out<<<dim3(32, 16), 256, 0, stream>>>(Ob, Wobf, out);
}

// Round 3
// 387.275 us; speedup vs baseline: 1.0262x; 1.0262x over previous
//
#include <hip/hip_runtime.h>

typedef unsigned short u16;
typedef unsigned int u32;
typedef __bf16 bf16x8 __attribute__((ext_vector_type(8)));
typedef float f32x4 __attribute__((ext_vector_type(4)));

// Problem constants: B=2, S=2048, D=2048, H=16, HD=128, F=3*H*HD=6144, M=B*S=4096

__device__ __forceinline__ u16 f2bf(float x) {
  __bf16 h = (__bf16)x;
  return __builtin_bit_cast(u16, h);
}

// async global->LDS, 16B per lane. LDS dest must be wave-uniform; HW scatters lane i to base+16*i.
__device__ __forceinline__ void async_copy16(void* lds, const void* g) {
  __builtin_amdgcn_global_load_lds((const __attribute__((address_space(1))) void*)g,
                                   (__attribute__((address_space(3))) void*)lds, 16, 0, 0);
}

// ---------------- fused cast fp32 -> bf16 for all three tensors ----------------
__global__ __launch_bounds__(256) void cast_all(const float* __restrict__ hidden,
                                                const float* __restrict__ wqkv,
                                                const float* __restrict__ wo,
                                                u16* __restrict__ xb,
                                                u16* __restrict__ wqb,
                                                u16* __restrict__ wob) {
  int i = blockIdx.x * 256 + threadIdx.x;  // 6291456 vec4 total
  const float* s;
  u16* d;
  int off;
  if (i < 2097152) { s = hidden; d = xb; off = i; }
  else if (i < 2097152 + 3145728) { s = wqkv; d = wqb; off = i - 2097152; }
  else { s = wo; d = wob; off = i - (2097152 + 3145728); }
  float4 v = ((const float4*)s)[off];
  ushort4 o;
  o.x = f2bf(v.x); o.y = f2bf(v.y); o.z = f2bf(v.z); o.w = f2bf(v.w);
  ((ushort4*)d)[off] = o;
}

// ---------------- QKV projection GEMM (256x256x64, 8-wave, 8-phase) + fused RoPE ------
// C[m,f] = sum_d X[m,d]*W[f,d]. M=4096, N=6144, K=2048. 8-phase counted-vmcnt schedule
// (m201 ledger: vmcnt(6) at ph4/ph8, youngest waited load 3 phases old — verified
// non-binding in r1/r2 A/B). Round-3 change: ks-SPLIT clusters with counted lgkm.
// r2 accounting: per-iter 11.25k cyc = MFMA 4.1k + LDS drain 6.8k, nearly serialized
// (lockstep barrier + lgkmcnt(0) exposes the whole read burst). Split each 16-MFMA
// cluster into 2x8 by ks: issue ks0 reads | fence | ks1 reads | barrier |
// lgkmcnt(n_ks1) -> 8 MFMA(ks0) | lgkmcnt(0) -> 8 MFMA(ks1). The ks1 half of the
// drain overlaps sub-cluster-0's MFMA exec. DS completes in-order per wave; issue
// order pinned by asm memory-clobber fences; sched_barrier(0) after each lgkm wait
// (rule #18: hipcc hoists reg-only MFMA past inline-asm waitcnt). ks was already the
// outer accumulation loop -> bitwise-identical fp order.
// Two barriers per phase are REQUIRED: second barrier + lgkm0 guarantees all waves'
// reads of a piece completed before any wave's next stage can overwrite it (stage
// slots have 1-phase gaps). Per-row chunk-XOR swizzle keeps ds_read_b128 conflict-free.
// Wave->column remap keeps RoPE pairs (hd,hd+64) in-lane and head/which wave-uniform.

__device__ __forceinline__ void lda_ks(bf16x8 (&af)[4][2], const u16* base, int row, int c,
                                       int ks) {
#pragma unroll
  for (int mf = 0; mf < 4; mf++) af[mf][ks] = *(const bf16x8*)(base + (row + mf * 16) * 64 + c);
}

__device__ __forceinline__ void ldb_ks(bf16x8 (&bfr)[2][2], const u16* base, int row, int c,
                                       int ks) {
#pragma unroll
  for (int nf = 0; nf < 2; nf++) bfr[nf][ks] = *(const bf16x8*)(base + (row + nf * 16) * 64 + c);
}

#define FENCE() asm volatile("" ::: "memory")
#define LGKM0() asm volatile("s_waitcnt lgkmcnt(0)" ::: "memory")
#define LGKM2() asm volatile("s_waitcnt lgkmcnt(2)" ::: "memory")
#define LGKM4() asm volatile("s_waitcnt lgkmcnt(4)" ::: "memory")
#define LGKM6() asm volatile("s_waitcnt lgkmcnt(6)" ::: "memory")
#define VMW6() asm volatile("s_waitcnt vmcnt(6)" ::: "memory")
#define VMW0() asm volatile("s_waitcnt vmcnt(0)" ::: "memory")
#define BAR() __builtin_amdgcn_s_barrier()
#define SBAR() __builtin_amdgcn_sched_barrier(0)

#define MFMA_H(MH, NH, KS)                                                               \
  _Pragma("unroll") for (int mf = 0; mf < 4; mf++)                                       \
  _Pragma("unroll") for (int nf = 0; nf < 2; nf++)                                       \
      acc[(MH)*4 + mf][(NH)*2 + nf] = __builtin_amdgcn_mfma_f32_16x16x32_bf16(           \
          af[mf][KS], bfr[nf][KS], acc[(MH)*4 + mf][(NH)*2 + nf], 0, 0, 0);

// phase execute: barrier, counted-lgkm ks0 sub-cluster, lgkm0 ks1 sub-cluster, tail, barrier
#define PH_SPLIT(MH, NH, W1, TAIL)      \
  BAR();                                \
  W1; SBAR();                           \
  __builtin_amdgcn_s_setprio(1);        \
  MFMA_H(MH, NH, 0);                    \
  LGKM0(); SBAR();                      \
  MFMA_H(MH, NH, 1);                    \
  __builtin_amdgcn_s_setprio(0);        \
  TAIL;                                 \
  FENCE(); BAR()

// stage one half-tile (128 rows x 64 cols): 2 global_load_lds per thread
#define STG_A(DB, H, KT)                                                                   \
  {                                                                                        \
    async_copy16(ldsA + (DB)*32768 + ((H)*64 + w8) * 128, Ag + aoff[H][0] + (KT)*128);     \
    async_copy16(ldsA + (DB)*32768 + (128 + (H)*64 + w8) * 128, Ag + aoff[H][1] + (KT)*128); \
  }
#define STG_B(DB, H, KT)                                                                   \
  {                                                                                        \
    async_copy16(ldsB + (DB)*32768 + ((H)*64 + w8) * 128, Bg + boff[H][0] + (KT)*128);     \
    async_copy16(ldsB + (DB)*32768 + (128 + (H)*64 + w8) * 128, Bg + boff[H][1] + (KT)*128); \
  }

template <bool MORE>
__device__ __forceinline__ void qkv_iter(const u16* As, const u16* Bs, char* ldsA, char* ldsB,
                                         const char* Ag, const char* Bg,
                                         const u32 (&aoff)[2][2], const u32 (&boff)[2][2],
                                         int w8, int arow0, int brow0, int c0, int c1,
                                         int k1, int k2, int k3,
                                         bf16x8 (&af)[4][2], bf16x8 (&bfr)[2][2],
                                         f32x4 (&acc)[8][4]) {
  const int arow1 = arow0 + 256;
  const int brow1 = brow0 + 256;
  // ph1: buf0 quad(0,0) | stage buf1.B0 (k1 = 2t+1) | 12 reads -> lgkm(6)
  lda_ks(af, As, arow0, c0, 0); ldb_ks(bfr, Bs, brow0, c0, 0); FENCE();
  lda_ks(af, As, arow0, c1, 1); ldb_ks(bfr, Bs, brow0, c1, 1); FENCE();
  STG_B(1, 0, k1);
  PH_SPLIT(0, 0, LGKM6(), (void)0);
  // ph2: buf0 quad(0,1) | stage buf0.A0 (k2 = 2t+2) | 4 reads -> lgkm(2)
  ldb_ks(bfr, Bs, brow0 + 64, c0, 0); FENCE();
  ldb_ks(bfr, Bs, brow0 + 64, c1, 1); FENCE();
  if (MORE) { STG_A(0, 0, k2); }
  PH_SPLIT(0, 1, LGKM2(), (void)0);
  // ph3: buf0 quad(1,1) | stage buf0.B1 (k2) | 8 reads -> lgkm(4)
  lda_ks(af, As, arow0 + 64, c0, 0); FENCE();
  lda_ks(af, As, arow0 + 64, c1, 1); FENCE();
  if (MORE) { STG_B(0, 1, k2); }
  PH_SPLIT(1, 1, LGKM4(), (void)0);
  // ph4: buf0 quad(1,0) | stage buf0.A1 (k2) | drain buf1's 4 pieces
  ldb_ks(bfr, Bs, brow0, c0, 0); FENCE();
  ldb_ks(bfr, Bs, brow0, c1, 1); FENCE();
  if (MORE) { STG_A(0, 1, k2); }
  if (MORE) { PH_SPLIT(1, 0, LGKM2(), VMW6()); } else { PH_SPLIT(1, 0, LGKM2(), VMW0()); }
  // ph5: buf1 quad(0,0) | stage buf0.B0 (k2)
  lda_ks(af, As, arow1, c0, 0); ldb_ks(bfr, Bs, brow1, c0, 0); FENCE();
  lda_ks(af, As, arow1, c1, 1); ldb_ks(bfr, Bs, brow1, c1, 1); FENCE();
  if (MORE) { STG_B(0, 0, k2); }
  PH_SPLIT(0, 0, LGKM6(), (void)0);
  // ph6: buf1 quad(0,1) | stage buf1.A0 (k3 = 2t+3)
  ldb_ks(bfr, Bs, brow1 + 64, c0, 0); FENCE();
  ldb_ks(bfr, Bs, brow1 + 64, c1, 1); FENCE();
  if (MORE) { STG_A(1, 0, k3); }
  PH_SPLIT(0, 1, LGKM2(), (void)0);
  // ph7: buf1 quad(1,1) | stage buf1.B1 (k3)
  lda_ks(af, As, arow1 + 64, c0, 0); FENCE();
  lda_ks(af, As, arow1 + 64, c1, 1); FENCE();
  if (MORE) { STG_B(1, 1, k3); }
  PH_SPLIT(1, 1, LGKM4(), (void)0);
  // ph8: buf1 quad(1,0) | stage buf1.A1 (k3) | drain buf0-next
  ldb_ks(bfr, Bs, brow1, c0, 0); FENCE();
  ldb_ks(bfr, Bs, brow1, c1, 1); FENCE();
  if (MORE) { STG_A(1, 1, k3); }
  if (MORE) { PH_SPLIT(1, 0, LGKM2(), VMW6()); } else { PH_SPLIT(1, 0, LGKM2(), (void)0); }
}

__global__ __launch_bounds__(512, 2) void gemm_qkv(const u16* __restrict__ A,
                                                   const u16* __restrict__ W,
                                                   const float* __restrict__ cosb,
                                                   const float* __restrict__ sinb,
                                                   u16* __restrict__ Qb,
                                                   u16* __restrict__ Kb,
                                                   u16* __restrict__ Vt) {
  extern __shared__ u16 smem[];  // 131072 B dynamic
  u16* As = smem;                // [2 buf][256 rows][64], row-chunk-XOR swizzled
  u16* Bs = smem + 32768;
  char* ldsA = (char*)As;
  char* ldsB = (char*)Bs;
  const char* Ag = (const char*)A;
  const char* Bg = (const char*)W;

  const int tid = threadIdx.x;
  const int lane = tid & 63;
  const int w = tid >> 6;   // 0..7
  const int wm = w >> 2;    // 0..1
  const int wn = w & 3;     // 0..3
  const int r16 = lane & 15;
  const int g4 = lane >> 4;
  const int rsw = r16 & 7;
  const int w8 = w * 8;
  const int l8 = lane >> 3;
  const int gch = (lane & 7) ^ l8;  // global chunk feeding this lane's LDS slot

  // XCD-aware bijective swizzle (384 = 8*48)
  const int nblk = blockIdx.x;
  const int swz = (nblk & 7) * 48 + (nblk >> 3);
  const int bm = (swz & 15) * 256;
  const int by = swz >> 4;  // 0..23
  const int bn = by * 256;

  u32 aoff[2][2], boff[2][2];
#pragma unroll
  for (int h = 0; h < 2; h++) {
#pragma unroll
    for (int j = 0; j < 2; j++) {
      int row = j * 128 + h * 64 + w8 + l8;
      aoff[h][j] = (u32)(bm + row) * 4096u + (u32)gch * 16u;
      boff[h][j] = (u32)(bn + row) * 4096u + (u32)gch * 16u;
    }
  }

  const int c0 = (g4 ^ rsw) * 8;
  const int c1 = ((4 + g4) ^ rsw) * 8;
  const int arow0 = wm * 128 + r16;
  const int brow0 = (wn >> 1) * 128 + (wn & 1) * 32 + r16;

  bf16x8 af[4][2], bfr[2][2];
  f32x4 acc[8][4];
  const f32x4 fzero = {0.0f, 0.0f, 0.0f, 0.0f};
#pragma unroll
  for (int i = 0; i < 8; i++)
#pragma unroll
    for (int j = 0; j < 4; j++) acc[i][j] = fzero;

  // prologue: buf0 (tile 0, all 4 pieces) then buf1 (tile 1: A0, B1, A1).
  // VMW6 drains the 4 oldest = buf0; residue {buf1.A0,B1,A1} matches steady state.
  STG_A(0, 0, 0); STG_B(0, 0, 0); STG_B(0, 1, 0); STG_A(0, 1, 0);
  STG_A(1, 0, 1); STG_B(1, 1, 1); STG_A(1, 1, 1);
  VMW6();
  FENCE(); BAR();

#pragma unroll 1
  for (int t = 0; t < 15; t++) {
    qkv_iter<true>(As, Bs, ldsA, ldsB, Ag, Bg, aoff, boff, w8, arow0, brow0, c0, c1,
                   2 * t + 1, 2 * t + 2, 2 * t + 3, af, bfr, acc);
  }
  qkv_iter<false>(As, Bs, ldsA, ldsB, Ag, Bg, aoff, boff, w8, arow0, brow0, c0, c1,
                  31, 31, 31, af, bfr, acc);

  // ---- epilogue: RoPE (Q,K) / transpose-scatter (V). head/which wave-uniform.
  const int blk128 = by * 2 + (wn >> 1);
  const int which = blk128 % 3;
  const int head = blk128 / 3;
  const float qs = (which == 0) ? 0.08838834764831845f * 1.4426950408889634f : 1.0f;
  const int hb = (wn & 1) * 32;

#pragma unroll
  for (int mi = 0; mi < 8; mi++) {
#pragma unroll
    for (int r = 0; r < 4; r++) {
      int row = bm + wm * 128 + mi * 16 + g4 * 4 + r;  // global m = b*S+s
      int bb = row >> 11;
      int s = row & 2047;
      size_t bhIdx = (size_t)(bb * 16 + head);
      if (which == 2) {
#pragma unroll
        for (int ni = 0; ni < 4; ni++) {
          int hd = hb + (ni & 1) * 16 + (ni >> 1) * 64 + r16;
          Vt[(bhIdx * 128 + hd) * 2048 + s] = f2bf(acc[mi][ni][r]);  // V^T: [bh][hd][s]
        }
      } else {
        u16* dst = (which ? Kb : Qb) + (bhIdx * 2048 + (size_t)s) * 128;
#pragma unroll
        for (int ni = 0; ni < 2; ni++) {
          int hd = hb + ni * 16 + r16;  // <64; pair is hd+64 in acc[mi][ni+2]
          float c = cosb[s * 128 + hd] * qs;
          float sn = sinb[s * 128 + hd] * qs;
          float x1 = acc[mi][ni][r], x2 = acc[mi][ni + 2][r];
          dst[hd] = f2bf(x1 * c - x2 * sn);
          dst[hd + 64] = f2bf(x2 * c + x1 * sn);
        }
      }
    }
  }
}

#undef STG_A
#undef STG_B
#undef MFMA_H
#undef PH_SPLIT

// ---------------- Flash attention: 128-query x 128-key tiles, 512 threads --------------
// (unchanged)
__global__ __launch_bounds__(512) void flash_attn(const u16* __restrict__ Q,
                                                  const u16* __restrict__ K,
                                                  const u16* __restrict__ Vt,
                                                  u16* __restrict__ O) {
  __shared__ __align__(16) u16 Ks[2][128 * 128];
  __shared__ __align__(16) u16 Vs[2][128 * 128];
  __shared__ __align__(16) u16 Ps[8 * 16 * 64];  // per-wave [q][64 keys], XOR-swizzled
  const int tid = threadIdx.x;
  const int lane = tid & 63;
  const int wave = tid >> 6;  // 0..7
  const int bh = blockIdx.y;
  const int r16 = lane & 15;
  const int g4 = lane >> 4;
  const int rsw = r16 & 7;
  const u16* Qh = Q + (size_t)bh * 2048 * 128;
  const u16* Kh = K + (size_t)bh * 2048 * 128;
  const u16* Vh = Vt + (size_t)bh * 128 * 2048;
  const int b = bh >> 4;
  const int h = bh & 15;

  int koff[4], voff[4], ldsOff[4];
#pragma unroll
  for (int i = 0; i < 4; i++) {
    int r = (wave * 4 + i) * 4 + (lane >> 4);  // 0..127
    int c = (lane & 15) ^ (r & 7);
    koff[i] = r * 128 + c * 8;
    voff[i] = r * 2048 + c * 8;
    ldsOff[i] = (wave * 4 + i) * 512;
  }

#pragma unroll 1
  for (int pass = 0; pass < 2; pass++) {
    const int T = pass == 0 ? (int)blockIdx.x : 15 - (int)blockIdx.x;
    const int qg = T * 128 + wave * 16 + r16;
    const int nk = T + 1;

    bf16x8 qf[4];
#pragma unroll
    for (int ks = 0; ks < 4; ks++)
      qf[ks] = *(const bf16x8*)(Qh + (size_t)qg * 128 + ks * 32 + g4 * 8);

    f32x4 o[8];
    f32x4 zero = {0.0f, 0.0f, 0.0f, 0.0f};
#pragma unroll
    for (int c = 0; c < 8; c++) o[c] = zero;
    float m_i = -__builtin_inff();
    float l_i = 0.0f;

    __syncthreads();
#pragma unroll
    for (int i = 0; i < 4; i++) {
      async_copy16(&Ks[0][ldsOff[i]], Kh + koff[i]);
      async_copy16(&Vs[0][ldsOff[i]], Vh + voff[i]);
    }

    int cur = 0;
    for (int u = 0; u < nk; u++) {
      __syncthreads();
      if (u + 1 < nk) {
#pragma unroll
        for (int i = 0; i < 4; i++) {
          async_copy16(&Ks[cur ^ 1][ldsOff[i]], Kh + (size_t)(u + 1) * 16384 + koff[i]);
          async_copy16(&Vs[cur ^ 1][ldsOff[i]], Vh + (size_t)(u + 1) * 128 + voff[i]);
        }
      }

      f32x4 sacc[8];
#pragma unroll
      for (int n = 0; n < 8; n++) sacc[n] = zero;
#pragma unroll
      for (int n = 0; n < 8; n++) {
#pragma unroll
        for (int ks = 0; ks < 4; ks++) {
          bf16x8 kf = *(const bf16x8*)(&Ks[cur][(n * 16 + r16) * 128 + ((ks * 4 + g4) ^ rsw) * 8]);
          sacc[n] = __builtin_amdgcn_mfma_f32_16x16x32_bf16(kf, qf[ks], sacc[n], 0, 0, 0);
        }
      }

      if (u == nk - 1) {
#pragma unroll
        for (int n = 0; n < 8; n++)
#pragma unroll
          for (int r = 0; r < 4; r++) {
            int key = u * 128 + 16 * n + g4 * 4 + r;
            if (key > qg) sacc[n][r] = -__builtin_inff();
          }
      }
      float vmax = -__builtin_inff();
#pragma unroll
      for (int n = 0; n < 8; n++)
#pragma unroll
        for (int r = 0; r < 4; r++) vmax = fmaxf(vmax, sacc[n][r]);
      vmax = fmaxf(vmax, __shfl_xor(vmax, 16));
      vmax = fmaxf(vmax, __shfl_xor(vmax, 32));
      float mn = fmaxf(m_i, vmax);
      float alpha = exp2f(m_i - mn);
      m_i = mn;

#pragma unroll
      for (int c = 0; c < 8; c++)
#pragma unroll
        for (int r = 0; r < 4; r++) o[c][r] *= alpha;

      float ssum = 0.0f;
      u16* Pw = &Ps[wave * 1024];
#pragma unroll
      for (int half = 0; half < 2; half++) {
#pragma unroll
        for (int nl = 0; nl < 4; nl++) {
          int n = half * 4 + nl;
          float p0 = exp2f(sacc[n][0] - mn);
          float p1 = exp2f(sacc[n][1] - mn);
          float p2 = exp2f(sacc[n][2] - mn);
          float p3 = exp2f(sacc[n][3] - mn);
          ssum += (p0 + p1) + (p2 + p3);
          ushort4 pk;
          pk.x = f2bf(p0); pk.y = f2bf(p1); pk.z = f2bf(p2); pk.w = f2bf(p3);
          *(ushort4*)(&Pw[r16 * 64 + ((2 * nl + (g4 >> 1)) ^ rsw) * 8 + (g4 & 1) * 4]) = pk;
        }
#pragma unroll
        for (int ks2 = 0; ks2 < 2; ks2++) {
          bf16x8 pf = *(const bf16x8*)(&Pw[r16 * 64 + ((ks2 * 4 + g4) ^ rsw) * 8]);
          int kv = half * 2 + ks2;
#pragma unroll
          for (int c = 0; c < 8; c++) {
            bf16x8 vf = *(const bf16x8*)(&Vs[cur][(c * 16 + r16) * 128 + ((kv * 4 + g4) ^ rsw) * 8]);
            o[c] = __builtin_amdgcn_mfma_f32_16x16x32_bf16(vf, pf, o[c], 0, 0, 0);
          }
        }
      }
      ssum += __shfl_xor(ssum, 16);
      ssum += __shfl_xor(ssum, 32);
      l_i = l_i * alpha + ssum;
      cur ^= 1;
    }

    float rl = 1.0f / l_i;
    u16* dst = O + ((size_t)(b * 2048 + qg)) * 2048 + h * 128;
#pragma unroll
    for (int c = 0; c < 8; c++) {
      ushort4 pk;
      pk.x = f2bf(o[c][0] * rl);
      pk.y = f2bf(o[c][1] * rl);
      pk.z = f2bf(o[c][2] * rl);
      pk.w = f2bf(o[c][3] * rl);
      *(ushort4*)(dst + c * 16 + g4 * 4) = pk;
    }
  }
}

// ---------------- Output projection GEMM (unchanged) ----------------
__global__ __launch_bounds__(256) void gemm_out(const u16* __restrict__ A,
                                                const u16* __restrict__ W,
                                                float* __restrict__ out) {
  __shared__ __align__(16) u16 As[128 * 64];
  __shared__ __align__(16) u16 Bs[128 * 64];
  const int tid = threadIdx.x;
  const int lane = tid & 63;
  const int wave = tid >> 6;
  const int wm = (wave >> 1) * 64;
  const int wn = (wave & 1) * 64;
  const int r16 = lane & 15;
  const int g4 = lane >> 4;
  const int rsw = r16 & 7;
  const int bm = blockIdx.x * 128;
  const int bn = blockIdx.y * 128;

  size_t aoff[4], boff[4];
  u16* ldsA[4];
  u16* ldsB[4];
#pragma unroll
  for (int i = 0; i < 4; i++) {
    int row = wave * 32 + i * 8 + (lane >> 3);
    int c = (lane & 7) ^ (row & 7);
    aoff[i] = (size_t)(bm + row) * 2048 + c * 8;
    boff[i] = (size_t)(bn + row) * 2048 + c * 8;
    ldsA[i] = &As[(wave * 4 + i) * 512];
    ldsB[i] = &Bs[(wave * 4 + i) * 512];
  }

  f32x4 acc[4][4];
  f32x4 zero = {0.0f, 0.0f, 0.0f, 0.0f};
#pragma unroll
  for (int m = 0; m < 4; m++)
#pragma unroll
    for (int n = 0; n < 4; n++) acc[m][n] = zero;

  for (int kt = 0; kt < 2048; kt += 64) {
    __syncthreads();
#pragma unroll
    for (int i = 0; i < 4; i++) {
      async_copy16(ldsA[i], A + aoff[i] + kt);
      async_copy16(ldsB[i], W + boff[i] + kt);
    }
    __syncthreads();
#pragma unroll
    for (int ks = 0; ks < 2; ks++) {
      bf16x8 af[4], bfr[4];
#pragma unroll
      for (int m = 0; m < 4; m++)
        af[m] = *(const bf16x8*)(&As[(wm + m * 16 + r16) * 64 + ((ks * 4 + g4) ^ rsw) * 8]);
#pragma unroll
      for (int n = 0; n < 4; n++)
        bfr[n] = *(const bf16x8*)(&Bs[(wn + n * 16 + r16) * 64 + ((ks * 4 + g4) ^ rsw) * 8]);
#pragma unroll
      for (int m = 0; m < 4; m++)
#pragma unroll
        for (int n = 0; n < 4; n++)
          acc[m][n] = __builtin_amdgcn_mfma_f32_16x16x32_bf16(af[m], bfr[n], acc[m][n], 0, 0, 0);
    }
  }

#pragma unroll
  for (int m = 0; m < 4; m++) {
#pragma unroll
    for (int n = 0; n < 4; n++) {
#pragma unroll
      for (int r = 0; r < 4; r++) {
        int row = bm + wm + m * 16 + g4 * 4 + r;
        int col = bn + wn + n * 16 + r16;
        out[(size_t)row * 2048 + col] = acc[m][n][r];
      }
    }
  }
}

extern "C" void kernel_launch(void* const* d_in, const int* in_sizes, int n_in,
                              void* d_out, int out_size, void* d_ws, size_t ws_size,
                              hipStream_t stream) {
  const float* hidden = (const float*)d_in[0];  // [2,2048,2048]
  const float* cosb   = (const float*)d_in[1];  // [2048,128]
  const float* sinb   = (const float*)d_in[2];  // [2048,128]
  const float* w_qkv  = (const float*)d_in[3];  // [3,2048,2048] -> flat [6144,2048]
  const float* w_o    = (const float*)d_in[4];  // [2048,2048]
  float* out = (float*)d_out;                   // [2,2048,2048] fp32

  char* ws = (char*)d_ws;
  u16* Xbf    = (u16*)(ws);                 // 16 MiB
  u16* Wqkvbf = (u16*)(ws + 16777216);      // 24 MiB
  u16* Wobf   = (u16*)(ws + 41943040);      // 8 MiB
  u16* Qb     = (u16*)(ws + 50331648);      // [B,H,S,HD] 16 MiB
  u16* Kb     = (u16*)(ws + 67108864);      // [B,H,S,HD] 16 MiB
  u16* Vt     = (u16*)(ws + 83886080);      // [B,H,HD,S] 16 MiB
  u16* Ob     = (u16*)(ws + 100663296);     // [B,S,H,HD] 16 MiB (end 112 MiB)

  static int attr_done = 0;
  if (!attr_done) {
    (void)hipFuncSetAttribute((const void*)gemm_qkv,
                              hipFuncAttributeMaxDynamicSharedMemorySize, 131072);
    attr_done = 1;
  }

  cast_all<<<24576, 256, 0, stream>>>(hidden, w_qkv, w_o, Xbf, Wqkvbf, Wobf);
  gemm_qkv<<<384, 512, 131072, stream>>>(Xbf, Wqkvbf, cosb, sinb, Qb, Kb, Vt);
  flash_attn<<<dim3(8, 32), 512, 0, stream>>>(Qb, Kb, Vt, Ob);
  gemm_out<<<dim3(32, 16), 256, 0, stream>>>(Ob, Wobf, out);
}

// Round 4
// 369.036 us; speedup vs baseline: 1.0769x; 1.0494x over previous
//
#include <hip/hip_runtime.h>

typedef unsigned short u16;
typedef unsigned int u32;
typedef __bf16 bf16x8 __attribute__((ext_vector_type(8)));
typedef float f32x4 __attribute__((ext_vector_type(4)));

// Problem constants: B=2, S=2048, D=2048, H=16, HD=128, F=3*H*HD=6144, M=B*S=4096
// f decomposes as f = head*384 + which*128 + hd (reference reshapes to [B,S,H,3*HD]);
// f-block (128 cols) fb -> which = fb%3, head = fb/3.

__device__ __forceinline__ u16 f2bf(float x) {
  __bf16 h = (__bf16)x;
  return __builtin_bit_cast(u16, h);
}

// async global->LDS, 16B per lane. LDS dest must be wave-uniform; HW scatters lane i to base+16*i.
__device__ __forceinline__ void async_copy16(void* lds, const void* g) {
  __builtin_amdgcn_global_load_lds((const __attribute__((address_space(1))) void*)g,
                                   (__attribute__((address_space(3))) void*)lds, 16, 0, 0);
}

// ---------------- fused cast fp32 -> bf16 for all three tensors ----------------
__global__ __launch_bounds__(256) void cast_all(const float* __restrict__ hidden,
                                                const float* __restrict__ wqkv,
                                                const float* __restrict__ wo,
                                                u16* __restrict__ xb,
                                                u16* __restrict__ wqb,
                                                u16* __restrict__ wob) {
  int i = blockIdx.x * 256 + threadIdx.x;  // 6291456 vec4 total
  const float* s;
  u16* d;
  int off;
  if (i < 2097152) { s = hidden; d = xb; off = i; }
  else if (i < 2097152 + 3145728) { s = wqkv; d = wqb; off = i - 2097152; }
  else { s = wo; d = wob; off = i - (2097152 + 3145728); }
  float4 v = ((const float4*)s)[off];
  ushort4 o;
  o.x = f2bf(v.x); o.y = f2bf(v.y); o.z = f2bf(v.z); o.w = f2bf(v.w);
  ((ushort4*)d)[off] = o;
}

// ---------------- QKV projection GEMM + fused RoPE — persistent 1.5-tile blocks -------
// C[m,f] = sum_d X[m,d]*W[f,d]. M=4096, N=6144, K=2048. 384 logical 256x256 tiles on a
// 256-block grid (1 block/CU, exactly one dispatch generation -> no 1.5-round tail,
// which cost 25% in r1-r3). Each block: one FULL 256x256 tile (8-phase loop, unchanged
// from r3) + one HALF 128x256 tile (M-split of tiles with by>=16; 128 tiles x 2 halves
// = 256 halves, one per block; uniform 1.5 tile-units per block). Half tile reuses the
// full tile's B-column mapping -> identical RoPE pairing and epilogue formulas.
// Per-row chunk-XOR swizzle keeps ds_read_b128 conflict-free (measured 0 conflicts).

__device__ __forceinline__ void lda_ks(bf16x8 (&af)[4][2], const u16* base, int row, int c,
                                       int ks) {
#pragma unroll
  for (int mf = 0; mf < 4; mf++) af[mf][ks] = *(const bf16x8*)(base + (row + mf * 16) * 64 + c);
}

__device__ __forceinline__ void ldb_ks(bf16x8 (&bfr)[2][2], const u16* base, int row, int c,
                                       int ks) {
#pragma unroll
  for (int nf = 0; nf < 2; nf++) bfr[nf][ks] = *(const bf16x8*)(base + (row + nf * 16) * 64 + c);
}

#define FENCE() asm volatile("" ::: "memory")
#define LGKM0() asm volatile("s_waitcnt lgkmcnt(0)" ::: "memory")
#define LGKM2() asm volatile("s_waitcnt lgkmcnt(2)" ::: "memory")
#define LGKM4() asm volatile("s_waitcnt lgkmcnt(4)" ::: "memory")
#define LGKM6() asm volatile("s_waitcnt lgkmcnt(6)" ::: "memory")
#define VMW6() asm volatile("s_waitcnt vmcnt(6)" ::: "memory")
#define VMW0() asm volatile("s_waitcnt vmcnt(0)" ::: "memory")
#define BAR() __builtin_amdgcn_s_barrier()
#define SBAR() __builtin_amdgcn_sched_barrier(0)

#define MFMA_H(MH, NH, KS)                                                               \
  _Pragma("unroll") for (int mf = 0; mf < 4; mf++)                                       \
  _Pragma("unroll") for (int nf = 0; nf < 2; nf++)                                       \
      acc[(MH)*4 + mf][(NH)*2 + nf] = __builtin_amdgcn_mfma_f32_16x16x32_bf16(           \
          af[mf][KS], bfr[nf][KS], acc[(MH)*4 + mf][(NH)*2 + nf], 0, 0, 0);

// half-tile MFMA: acc rows 0..3, n-frag base NB (0 or 2)
#define MFMA_HALF(NB)                                                                    \
  _Pragma("unroll") for (int ks = 0; ks < 2; ks++)                                       \
  _Pragma("unroll") for (int mf = 0; mf < 4; mf++)                                       \
  _Pragma("unroll") for (int nf = 0; nf < 2; nf++)                                       \
      acc[mf][(NB) + nf] = __builtin_amdgcn_mfma_f32_16x16x32_bf16(                      \
          af[mf][ks], bfr[nf][ks], acc[mf][(NB) + nf], 0, 0, 0);

// phase execute: barrier, counted-lgkm ks0 sub-cluster, lgkm0 ks1 sub-cluster, tail, barrier
#define PH_SPLIT(MH, NH, W1, TAIL)      \
  BAR();                                \
  W1; SBAR();                           \
  __builtin_amdgcn_s_setprio(1);        \
  MFMA_H(MH, NH, 0);                    \
  LGKM0(); SBAR();                      \
  MFMA_H(MH, NH, 1);                    \
  __builtin_amdgcn_s_setprio(0);        \
  TAIL;                                 \
  FENCE(); BAR()

// stage one half-tile (128 rows x 64 cols): 2 global_load_lds per thread
#define STG_A(DB, H, KT)                                                                   \
  {                                                                                        \
    async_copy16(ldsA + (DB)*32768 + ((H)*64 + w8) * 128, Ag + aoff[H][0] + (KT)*128);     \
    async_copy16(ldsA + (DB)*32768 + (128 + (H)*64 + w8) * 128, Ag + aoff[H][1] + (KT)*128); \
  }
#define STG_B(DB, H, KT)                                                                   \
  {                                                                                        \
    async_copy16(ldsB + (DB)*32768 + ((H)*64 + w8) * 128, Bg + boff[H][0] + (KT)*128);     \
    async_copy16(ldsB + (DB)*32768 + (128 + (H)*64 + w8) * 128, Bg + boff[H][1] + (KT)*128); \
  }
// half-tile staging: A = 128 rows (2 gll), B = full 256 rows via 2 calls (as STG_B)
#define STG_AH(DB, KT)                                                                     \
  {                                                                                        \
    async_copy16(ldsA + (DB)*32768 + (w8) * 128, Ag + aoffH[0] + (KT)*128);                \
    async_copy16(ldsA + (DB)*32768 + (64 + w8) * 128, Ag + aoffH[1] + (KT)*128);           \
  }
#define STG_BH(DB, H, KT)                                                                  \
  {                                                                                        \
    async_copy16(ldsB + (DB)*32768 + ((H)*64 + w8) * 128, Bg + boffH[H][0] + (KT)*128);    \
    async_copy16(ldsB + (DB)*32768 + (128 + (H)*64 + w8) * 128, Bg + boffH[H][1] + (KT)*128); \
  }

template <bool MORE>
__device__ __forceinline__ void qkv_iter(const u16* As, const u16* Bs, char* ldsA, char* ldsB,
                                         const char* Ag, const char* Bg,
                                         const u32 (&aoff)[2][2], const u32 (&boff)[2][2],
                                         int w8, int arow0, int brow0, int c0, int c1,
                                         int k1, int k2, int k3,
                                         bf16x8 (&af)[4][2], bf16x8 (&bfr)[2][2],
                                         f32x4 (&acc)[8][4]) {
  const int arow1 = arow0 + 256;
  const int brow1 = brow0 + 256;
  // ph1: buf0 quad(0,0) | stage buf1.B0 (k1 = 2t+1) | 12 reads -> lgkm(6)
  lda_ks(af, As, arow0, c0, 0); ldb_ks(bfr, Bs, brow0, c0, 0); FENCE();
  lda_ks(af, As, arow0, c1, 1); ldb_ks(bfr, Bs, brow0, c1, 1); FENCE();
  STG_B(1, 0, k1);
  PH_SPLIT(0, 0, LGKM6(), (void)0);
  // ph2: buf0 quad(0,1) | stage buf0.A0 (k2 = 2t+2) | 4 reads -> lgkm(2)
  ldb_ks(bfr, Bs, brow0 + 64, c0, 0); FENCE();
  ldb_ks(bfr, Bs, brow0 + 64, c1, 1); FENCE();
  if (MORE) { STG_A(0, 0, k2); }
  PH_SPLIT(0, 1, LGKM2(), (void)0);
  // ph3: buf0 quad(1,1) | stage buf0.B1 (k2) | 8 reads -> lgkm(4)
  lda_ks(af, As, arow0 + 64, c0, 0); FENCE();
  lda_ks(af, As, arow0 + 64, c1, 1); FENCE();
  if (MORE) { STG_B(0, 1, k2); }
  PH_SPLIT(1, 1, LGKM4(), (void)0);
  // ph4: buf0 quad(1,0) | stage buf0.A1 (k2) | drain buf1's 4 pieces
  ldb_ks(bfr, Bs, brow0, c0, 0); FENCE();
  ldb_ks(bfr, Bs, brow0, c1, 1); FENCE();
  if (MORE) { STG_A(0, 1, k2); }
  if (MORE) { PH_SPLIT(1, 0, LGKM2(), VMW6()); } else { PH_SPLIT(1, 0, LGKM2(), VMW0()); }
  // ph5: buf1 quad(0,0) | stage buf0.B0 (k2)
  lda_ks(af, As, arow1, c0, 0); ldb_ks(bfr, Bs, brow1, c0, 0); FENCE();
  lda_ks(af, As, arow1, c1, 1); ldb_ks(bfr, Bs, brow1, c1, 1); FENCE();
  if (MORE) { STG_B(0, 0, k2); }
  PH_SPLIT(0, 0, LGKM6(), (void)0);
  // ph6: buf1 quad(0,1) | stage buf1.A0 (k3 = 2t+3)
  ldb_ks(bfr, Bs, brow1 + 64, c0, 0); FENCE();
  ldb_ks(bfr, Bs, brow1 + 64, c1, 1); FENCE();
  if (MORE) { STG_A(1, 0, k3); }
  PH_SPLIT(0, 1, LGKM2(), (void)0);
  // ph7: buf1 quad(1,1) | stage buf1.B1 (k3)
  lda_ks(af, As, arow1 + 64, c0, 0); FENCE();
  lda_ks(af, As, arow1 + 64, c1, 1); FENCE();
  if (MORE) { STG_B(1, 1, k3); }
  PH_SPLIT(1, 1, LGKM4(), (void)0);
  // ph8: buf1 quad(1,0) | stage buf1.A1 (k3) | drain buf0-next
  ldb_ks(bfr, Bs, brow1, c0, 0); FENCE();
  ldb_ks(bfr, Bs, brow1, c1, 1); FENCE();
  if (MORE) { STG_A(1, 1, k3); }
  if (MORE) { PH_SPLIT(1, 0, LGKM2(), VMW6()); } else { PH_SPLIT(1, 0, LGKM2(), (void)0); }
}

__global__ __launch_bounds__(512, 2) void gemm_qkv(const u16* __restrict__ A,
                                                   const u16* __restrict__ W,
                                                   const float* __restrict__ cosb,
                                                   const float* __restrict__ sinb,
                                                   u16* __restrict__ Qb,
                                                   u16* __restrict__ Kb,
                                                   u16* __restrict__ Vt) {
  extern __shared__ u16 smem[];  // 131072 B dynamic
  u16* As = smem;                // [2 buf][256 rows][64], row-chunk-XOR swizzled
  u16* Bs = smem + 32768;        // u16 offset 32768 = byte 65536
  char* ldsA = (char*)As;
  char* ldsB = (char*)Bs;
  const char* Ag = (const char*)A;
  const char* Bg = (const char*)W;

  const int tid = threadIdx.x;
  const int lane = tid & 63;
  const int w = tid >> 6;   // 0..7
  const int wm = w >> 2;    // 0..1
  const int wn = w & 3;     // 0..3
  const int r16 = lane & 15;
  const int g4 = lane >> 4;
  const int rsw = r16 & 7;
  const int w8 = w * 8;
  const int l8 = lane >> 3;
  const int gch = (lane & 7) ^ l8;  // global chunk feeding this lane's LDS slot

  // XCD-aware bijective swizzle (256 = 8*32)
  const int nblk = blockIdx.x;
  const int swz = (nblk & 7) * 32 + (nblk >> 3);

  // ---- FULL tile: bm = (swz&15)*256, by = swz>>4 in [0,16) ----
  const int bm = (swz & 15) * 256;
  const int by = swz >> 4;
  const int bn = by * 256;

  u32 aoff[2][2], boff[2][2];
#pragma unroll
  for (int h = 0; h < 2; h++) {
#pragma unroll
    for (int j = 0; j < 2; j++) {
      int row = j * 128 + h * 64 + w8 + l8;
      aoff[h][j] = (u32)(bm + row) * 4096u + (u32)gch * 16u;
      boff[h][j] = (u32)(bn + row) * 4096u + (u32)gch * 16u;
    }
  }

  const int c0 = (g4 ^ rsw) * 8;
  const int c1 = ((4 + g4) ^ rsw) * 8;
  const int arow0 = wm * 128 + r16;
  const int brow0 = (wn >> 1) * 128 + (wn & 1) * 32 + r16;

  bf16x8 af[4][2], bfr[2][2];
  f32x4 acc[8][4];
  const f32x4 fzero = {0.0f, 0.0f, 0.0f, 0.0f};
#pragma unroll
  for (int i = 0; i < 8; i++)
#pragma unroll
    for (int j = 0; j < 4; j++) acc[i][j] = fzero;

  // prologue: buf0 (tile 0, all 4 pieces) then buf1 (tile 1: A0, B1, A1).
  // VMW6 drains the 4 oldest = buf0; residue {buf1.A0,B1,A1} matches steady state.
  STG_A(0, 0, 0); STG_B(0, 0, 0); STG_B(0, 1, 0); STG_A(0, 1, 0);
  STG_A(1, 0, 1); STG_B(1, 1, 1); STG_A(1, 1, 1);
  VMW6();
  FENCE(); BAR();

#pragma unroll 1
  for (int t = 0; t < 15; t++) {
    qkv_iter<true>(As, Bs, ldsA, ldsB, Ag, Bg, aoff, boff, w8, arow0, brow0, c0, c1,
                   2 * t + 1, 2 * t + 2, 2 * t + 3, af, bfr, acc);
  }
  qkv_iter<false>(As, Bs, ldsA, ldsB, Ag, Bg, aoff, boff, w8, arow0, brow0, c0, c1,
                  31, 31, 31, af, bfr, acc);

  // ---- epilogue (full): RoPE (Q,K) / transpose-scatter (V). head/which wave-uniform.
  {
    const int blk128 = by * 2 + (wn >> 1);
    const int which = blk128 % 3;
    const int head = blk128 / 3;
    const float qs = (which == 0) ? 0.08838834764831845f * 1.4426950408889634f : 1.0f;
    const int hb = (wn & 1) * 32;

#pragma unroll
    for (int mi = 0; mi < 8; mi++) {
#pragma unroll
      for (int r = 0; r < 4; r++) {
        int row = bm + wm * 128 + mi * 16 + g4 * 4 + r;  // global m = b*S+s
        int bb = row >> 11;
        int s = row & 2047;
        size_t bhIdx = (size_t)(bb * 16 + head);
        if (which == 2) {
#pragma unroll
          for (int ni = 0; ni < 4; ni++) {
            int hd = hb + (ni & 1) * 16 + (ni >> 1) * 64 + r16;
            Vt[(bhIdx * 128 + hd) * 2048 + s] = f2bf(acc[mi][ni][r]);  // V^T: [bh][hd][s]
          }
        } else {
          u16* dst = (which ? Kb : Qb) + (bhIdx * 2048 + (size_t)s) * 128;
#pragma unroll
          for (int ni = 0; ni < 2; ni++) {
            int hd = hb + ni * 16 + r16;  // <64; pair is hd+64 in acc[mi][ni+2]
            float c = cosb[s * 128 + hd] * qs;
            float sn = sinb[s * 128 + hd] * qs;
            float x1 = acc[mi][ni][r], x2 = acc[mi][ni + 2][r];
            dst[hd] = f2bf(x1 * c - x2 * sn);
            dst[hd + 64] = f2bf(x2 * c + x1 * sn);
          }
        }
      }
    }
  }

  // ---- HALF tile: 128x256 at rows hbm*256 + mh*128, cols hby*256 (by in [16,24)) ----
  // 256 halves <-> 256 blocks bijectively. Wave grid 2M x 4N -> 64x64 wave tiles;
  // A (64 rows x 64 k per wave) held fully in af; B n-halves read once each.
  // Simple double-buffered loop: per K-tile {BAR; stage next (6 gll); VMW6; BAR;
  // ph_a (A + B-half0 reads, 16 MFMA); ph_b (B-half1 reads, 16 MFMA)}.
  // VMW6 after issuing the new 6 drains exactly the previous K-tile's 6 -> buf ready.
  const int hbm = swz & 15;
  const int hby = 16 + ((swz >> 4) & 7);
  const int mh = swz >> 7;  // 0..1 (M half)
  const int hbn = hby * 256;

  u32 aoffH[2];
#pragma unroll
  for (int j = 0; j < 2; j++)
    aoffH[j] = (u32)(hbm * 256 + mh * 128 + j * 64 + w8 + l8) * 4096u + (u32)gch * 16u;
  u32 boffH[2][2];
#pragma unroll
  for (int h = 0; h < 2; h++)
#pragma unroll
    for (int j = 0; j < 2; j++)
      boffH[h][j] = (u32)(hbn + j * 128 + h * 64 + w8 + l8) * 4096u + (u32)gch * 16u;

#pragma unroll
  for (int i = 0; i < 4; i++)
#pragma unroll
    for (int j = 0; j < 4; j++) acc[i][j] = fzero;

  const int arowH = wm * 64 + r16;  // rows [0,128) of the half-tile A buffer

  // prologue: stage K-tile 0 into buf0 (A half: 2 gll; B full: 4 gll)
  STG_AH(0, 0); STG_BH(0, 0, 0); STG_BH(0, 1, 0);

#pragma unroll 1
  for (int kt = 0; kt < 32; kt++) {
    const int db = kt & 1;
    const u16* AsH = smem + db * 16384;          // byte offset db*32768 in A region
    const u16* BsH = smem + 32768 + db * 16384;  // byte offset 65536 + db*32768
    FENCE(); BAR();  // all waves done reading buf db^1 -> safe to overwrite
    if (kt < 31) {
      STG_AH(db ^ 1, kt + 1); STG_BH(db ^ 1, 0, kt + 1); STG_BH(db ^ 1, 1, kt + 1);
      VMW6();  // drains everything older than the 6 just issued (incl. buf db's stage)
    } else {
      VMW0();
    }
    FENCE(); BAR();  // all waves' waits passed -> buf db fully visible
    // ph_a: full A (8 reads) + B n-half 0 (4 reads) -> 16 MFMA into acc[*][0..1]
    lda_ks(af, AsH, arowH, c0, 0);
    lda_ks(af, AsH, arowH, c1, 1);
    ldb_ks(bfr, BsH, brow0, c0, 0);
    ldb_ks(bfr, BsH, brow0, c1, 1);
    LGKM0(); SBAR();
    __builtin_amdgcn_s_setprio(1);
    MFMA_HALF(0);
    __builtin_amdgcn_s_setprio(0);
    // ph_b: B n-half 1 (4 reads; +64 cols), reuse A -> 16 MFMA into acc[*][2..3]
    ldb_ks(bfr, BsH, brow0 + 64, c0, 0);
    ldb_ks(bfr, BsH, brow0 + 64, c1, 1);
    LGKM0(); SBAR();
    __builtin_amdgcn_s_setprio(1);
    MFMA_HALF(2);
    __builtin_amdgcn_s_setprio(0);
  }

  // ---- epilogue (half): same column mapping as full, mi range 4, rows offset by mh ----
  {
    const int blk128 = hby * 2 + (wn >> 1);
    const int which = blk128 % 3;
    const int head = blk128 / 3;
    const float qs = (which == 0) ? 0.08838834764831845f * 1.4426950408889634f : 1.0f;
    const int hb = (wn & 1) * 32;

#pragma unroll
    for (int mi = 0; mi < 4; mi++) {
#pragma unroll
      for (int r = 0; r < 4; r++) {
        int row = hbm * 256 + mh * 128 + wm * 64 + mi * 16 + g4 * 4 + r;  // global m
        int bb = row >> 11;
        int s = row & 2047;
        size_t bhIdx = (size_t)(bb * 16 + head);
        if (which == 2) {
#pragma unroll
          for (int ni = 0; ni < 4; ni++) {
            int hd = hb + (ni & 1) * 16 + (ni >> 1) * 64 + r16;
            Vt[(bhIdx * 128 + hd) * 2048 + s] = f2bf(acc[mi][ni][r]);  // V^T: [bh][hd][s]
          }
        } else {
          u16* dst = (which ? Kb : Qb) + (bhIdx * 2048 + (size_t)s) * 128;
#pragma unroll
          for (int ni = 0; ni < 2; ni++) {
            int hd = hb + ni * 16 + r16;  // <64; pair is hd+64 in acc[mi][ni+2]
            float c = cosb[s * 128 + hd] * qs;
            float sn = sinb[s * 128 + hd] * qs;
            float x1 = acc[mi][ni][r], x2 = acc[mi][ni + 2][r];
            dst[hd] = f2bf(x1 * c - x2 * sn);
            dst[hd + 64] = f2bf(x2 * c + x1 * sn);
          }
        }
      }
    }
  }
}

#undef STG_A
#undef STG_B
#undef STG_AH
#undef STG_BH
#undef MFMA_H
#undef MFMA_HALF
#undef PH_SPLIT

// ---------------- Flash attention: 128-query x 128-key tiles, 512 threads --------------
// (unchanged)
__global__ __launch_bounds__(512) void flash_attn(const u16* __restrict__ Q,
                                                  const u16* __restrict__ K,
                                                  const u16* __restrict__ Vt,
                                                  u16* __restrict__ O) {
  __shared__ __align__(16) u16 Ks[2][128 * 128];
  __shared__ __align__(16) u16 Vs[2][128 * 128];
  __shared__ __align__(16) u16 Ps[8 * 16 * 64];  // per-wave [q][64 keys], XOR-swizzled
  const int tid = threadIdx.x;
  const int lane = tid & 63;
  const int wave = tid >> 6;  // 0..7
  const int bh = blockIdx.y;
  const int r16 = lane & 15;
  const int g4 = lane >> 4;
  const int rsw = r16 & 7;
  const u16* Qh = Q + (size_t)bh * 2048 * 128;
  const u16* Kh = K + (size_t)bh * 2048 * 128;
  const u16* Vh = Vt + (size_t)bh * 128 * 2048;
  const int b = bh >> 4;
  const int h = bh & 15;

  int koff[4], voff[4], ldsOff[4];
#pragma unroll
  for (int i = 0; i < 4; i++) {
    int r = (wave * 4 + i) * 4 + (lane >> 4);  // 0..127
    int c = (lane & 15) ^ (r & 7);
    koff[i] = r * 128 + c * 8;
    voff[i] = r * 2048 + c * 8;
    ldsOff[i] = (wave * 4 + i) * 512;
  }

#pragma unroll 1
  for (int pass = 0; pass < 2; pass++) {
    const int T = pass == 0 ? (int)blockIdx.x : 15 - (int)blockIdx.x;
    const int qg = T * 128 + wave * 16 + r16;
    const int nk = T + 1;

    bf16x8 qf[4];
#pragma unroll
    for (int ks = 0; ks < 4; ks++)
      qf[ks] = *(const bf16x8*)(Qh + (size_t)qg * 128 + ks * 32 + g4 * 8);

    f32x4 o[8];
    f32x4 zero = {0.0f, 0.0f, 0.0f, 0.0f};
#pragma unroll
    for (int c = 0; c < 8; c++) o[c] = zero;
    float m_i = -__builtin_inff();
    float l_i = 0.0f;

    __syncthreads();
#pragma unroll
    for (int i = 0; i < 4; i++) {
      async_copy16(&Ks[0][ldsOff[i]], Kh + koff[i]);
      async_copy16(&Vs[0][ldsOff[i]], Vh + voff[i]);
    }

    int cur = 0;
    for (int u = 0; u < nk; u++) {
      __syncthreads();
      if (u + 1 < nk) {
#pragma unroll
        for (int i = 0; i < 4; i++) {
          async_copy16(&Ks[cur ^ 1][ldsOff[i]], Kh + (size_t)(u + 1) * 16384 + koff[i]);
          async_copy16(&Vs[cur ^ 1][ldsOff[i]], Vh + (size_t)(u + 1) * 128 + voff[i]);
        }
      }

      f32x4 sacc[8];
#pragma unroll
      for (int n = 0; n < 8; n++) sacc[n] = zero;
#pragma unroll
      for (int n = 0; n < 8; n++) {
#pragma unroll
        for (int ks = 0; ks < 4; ks++) {
          bf16x8 kf = *(const bf16x8*)(&Ks[cur][(n * 16 + r16) * 128 + ((ks * 4 + g4) ^ rsw) * 8]);
          sacc[n] = __builtin_amdgcn_mfma_f32_16x16x32_bf16(kf, qf[ks], sacc[n], 0, 0, 0);
        }
      }

      if (u == nk - 1) {
#pragma unroll
        for (int n = 0; n < 8; n++)
#pragma unroll
          for (int r = 0; r < 4; r++) {
            int key = u * 128 + 16 * n + g4 * 4 + r;
            if (key > qg) sacc[n][r] = -__builtin_inff();
          }
      }
      float vmax = -__builtin_inff();
#pragma unroll
      for (int n = 0; n < 8; n++)
#pragma unroll
        for (int r = 0; r < 4; r++) vmax = fmaxf(vmax, sacc[n][r]);
      vmax = fmaxf(vmax, __shfl_xor(vmax, 16));
      vmax = fmaxf(vmax, __shfl_xor(vmax, 32));
      float mn = fmaxf(m_i, vmax);
      float alpha = exp2f(m_i - mn);
      m_i = mn;

#pragma unroll
      for (int c = 0; c < 8; c++)
#pragma unroll
        for (int r = 0; r < 4; r++) o[c][r] *= alpha;

      float ssum = 0.0f;
      u16* Pw = &Ps[wave * 1024];
#pragma unroll
      for (int half = 0; half < 2; half++) {
#pragma unroll
        for (int nl = 0; nl < 4; nl++) {
          int n = half * 4 + nl;
          float p0 = exp2f(sacc[n][0] - mn);
          float p1 = exp2f(sacc[n][1] - mn);
          float p2 = exp2f(sacc[n][2] - mn);
          float p3 = exp2f(sacc[n][3] - mn);
          ssum += (p0 + p1) + (p2 + p3);
          ushort4 pk;
          pk.x = f2bf(p0); pk.y = f2bf(p1); pk.z = f2bf(p2); pk.w = f2bf(p3);
          *(ushort4*)(&Pw[r16 * 64 + ((2 * nl + (g4 >> 1)) ^ rsw) * 8 + (g4 & 1) * 4]) = pk;
        }
#pragma unroll
        for (int ks2 = 0; ks2 < 2; ks2++) {
          bf16x8 pf = *(const bf16x8*)(&Pw[r16 * 64 + ((ks2 * 4 + g4) ^ rsw) * 8]);
          int kv = half * 2 + ks2;
#pragma unroll
          for (int c = 0; c < 8; c++) {
            bf16x8 vf = *(const bf16x8*)(&Vs[cur][(c * 16 + r16) * 128 + ((kv * 4 + g4) ^ rsw) * 8]);
            o[c] = __builtin_amdgcn_mfma_f32_16x16x32_bf16(vf, pf, o[c], 0, 0, 0);
          }
        }
      }
      ssum += __shfl_xor(ssum, 16);
      ssum += __shfl_xor(ssum, 32);
      l_i = l_i * alpha + ssum;
      cur ^= 1;
    }

    float rl = 1.0f / l_i;
    u16* dst = O + ((size_t)(b * 2048 + qg)) * 2048 + h * 128;
#pragma unroll
    for (int c = 0; c < 8; c++) {
      ushort4 pk;
      pk.x = f2bf(o[c][0] * rl);
      pk.y = f2bf(o[c][1] * rl);
      pk.z = f2bf(o[c][2] * rl);
      pk.w = f2bf(o[c][3] * rl);
      *(ushort4*)(dst + c * 16 + g4 * 4) = pk;
    }
  }
}

// ---------------- Output projection GEMM (unchanged) ----------------
__global__ __launch_bounds__(256) void gemm_out(const u16* __restrict__ A,
                                                const u16* __restrict__ W,
                                                float* __restrict__ out) {
  __shared__ __align__(16) u16 As[128 * 64];
  __shared__ __align__(16) u16 Bs[128 * 64];
  const int tid = threadIdx.x;
  const int lane = tid & 63;
  const int wave = tid >> 6;
  const int wm = (wave >> 1) * 64;
  const int wn = (wave & 1) * 64;
  const int r16 = lane & 15;
  const int g4 = lane >> 4;
  const int rsw = r16 & 7;
  const int bm = blockIdx.x * 128;
  const int bn = blockIdx.y * 128;

  size_t aoff[4], boff[4];
  u16* ldsA[4];
  u16* ldsB[4];
#pragma unroll
  for (int i = 0; i < 4; i++) {
    int row = wave * 32 + i * 8 + (lane >> 3);
    int c = (lane & 7) ^ (row & 7);
    aoff[i] = (size_t)(bm + row) * 2048 + c * 8;
    boff[i] = (size_t)(bn + row) * 2048 + c * 8;
    ldsA[i] = &As[(wave * 4 + i) * 512];
    ldsB[i] = &Bs[(wave * 4 + i) * 512];
  }

  f32x4 acc[4][4];
  f32x4 zero = {0.0f, 0.0f, 0.0f, 0.0f};
#pragma unroll
  for (int m = 0; m < 4; m++)
#pragma unroll
    for (int n = 0; n < 4; n++) acc[m][n] = zero;

  for (int kt = 0; kt < 2048; kt += 64) {
    __syncthreads();
#pragma unroll
    for (int i = 0; i < 4; i++) {
      async_copy16(ldsA[i], A + aoff[i] + kt);
      async_copy16(ldsB[i], W + boff[i] + kt);
    }
    __syncthreads();
#pragma unroll
    for (int ks = 0; ks < 2; ks++) {
      bf16x8 af[4], bfr[4];
#pragma unroll
      for (int m = 0; m < 4; m++)
        af[m] = *(const bf16x8*)(&As[(wm + m * 16 + r16) * 64 + ((ks * 4 + g4) ^ rsw) * 8]);
#pragma unroll
      for (int n = 0; n < 4; n++)
        bfr[n] = *(const bf16x8*)(&Bs[(wn + n * 16 + r16) * 64 + ((ks * 4 + g4) ^ rsw) * 8]);
#pragma unroll
      for (int m = 0; m < 4; m++)
#pragma unroll
        for (int n = 0; n < 4; n++)
          acc[m][n] = __builtin_amdgcn_mfma_f32_16x16x32_bf16(af[m], bfr[n], acc[m][n], 0, 0, 0);
    }
  }

#pragma unroll
  for (int m = 0; m < 4; m++) {
#pragma unroll
    for (int n = 0; n < 4; n++) {
#pragma unroll
      for (int r = 0; r < 4; r++) {
        int row = bm + wm + m * 16 + g4 * 4 + r;
        int col = bn + wn + n * 16 + r16;
        out[(size_t)row * 2048 + col] = acc[m][n][r];
      }
    }
  }
}

extern "C" void kernel_launch(void* const* d_in, const int* in_sizes, int n_in,
                              void* d_out, int out_size, void* d_ws, size_t ws_size,
                              hipStream_t stream) {
  const float* hidden = (const float*)d_in[0];  // [2,2048,2048]
  const float* cosb   = (const float*)d_in[1];  // [2048,128]
  const float* sinb   = (const float*)d_in[2];  // [2048,128]
  const float* w_qkv  = (const float*)d_in[3];  // [3,2048,2048] -> flat [6144,2048]
  const float* w_o    = (const float*)d_in[4];  // [2048,2048]
  float* out = (float*)d_out;                   // [2,2048,2048] fp32

  char* ws = (char*)d_ws;
  u16* Xbf    = (u16*)(ws);                 // 16 MiB
  u16* Wqkvbf = (u16*)(ws + 16777216);      // 24 MiB
  u16* Wobf   = (u16*)(ws + 41943040);      // 8 MiB
  u16* Qb     = (u16*)(ws + 50331648);      // [B,H,S,HD] 16 MiB
  u16* Kb     = (u16*)(ws + 67108864);      // [B,H,S,HD] 16 MiB
  u16* Vt     = (u16*)(ws + 83886080);      // [B,H,HD,S] 16 MiB
  u16* Ob     = (u16*)(ws + 100663296);     // [B,S,H,HD] 16 MiB (end 112 MiB)

  static int attr_done = 0;
  if (!attr_done) {
    (void)hipFuncSetAttribute((const void*)gemm_qkv,
                              hipFuncAttributeMaxDynamicSharedMemorySize, 131072);
    attr_done = 1;
  }

  cast_all<<<24576, 256, 0, stream>>>(hidden, w_qkv, w_o, Xbf, Wqkvbf, Wobf);
  gemm_qkv<<<256, 512, 131072, stream>>>(Xbf, Wqkvbf, cosb, sinb, Qb, Kb, Vt);
  flash_attn<<<dim3(8, 32), 512, 0, stream>>>(Qb, Kb, Vt, Ob);
  gemm_out<<<dim3(32, 16), 256, 0, stream>>>(Ob, Wobf, out);
}